// Round 5
// baseline (89.907 us; speedup 1.0000x reference)
//
#include <hip/hip_runtime.h>
#include <stdint.h>

#define NB    128
#define NSTEP 63
#define DT    0.00390625f
#define TSC   2.8853900817779268f   // 2*log2(e): folded into GEMM1 weights

typedef __attribute__((ext_vector_type(8))) short bf16x8;
typedef __attribute__((ext_vector_type(4))) float f32x4;
typedef __attribute__((ext_vector_type(2))) float f32x2;

union Frag { bf16x8 v; uint32_t u[4]; };

__device__ __forceinline__ short f2bf(float f) {
    uint32_t u = __float_as_uint(f);
    u += 0x7FFF + ((u >> 16) & 1);          // round-to-nearest-even
    return (short)(u >> 16);
}

__device__ __forceinline__ uint32_t pk_bf16(float lo, float hi) {
    uint32_t r;
    asm("v_cvt_pk_bf16_f32 %0, %1, %2" : "=v"(r) : "v"(lo), "v"(hi));
    return r;
}

// Pairwise tanh on pre-scaled inputs y = 2*log2e*preact: tanh = 1 - 2/(2^y+1).
// Builtins only (TRANS wait-state hazard: inline-asm exp broke round 3).
// add/fma parts vectorized to v_pk_* ops.
__device__ __forceinline__ f32x2 tanh2_sc(float y0, float y1) {
    f32x2 e = { __builtin_amdgcn_exp2f(y0), __builtin_amdgcn_exp2f(y1) };
    f32x2 ep = e + (f32x2)1.0f;
    f32x2 r = { __builtin_amdgcn_rcpf(ep.x), __builtin_amdgcn_rcpf(ep.y) };
    return __builtin_elementwise_fma(r, (f32x2)(-2.0f), (f32x2)(1.0f));
}

// Block = 4 waves, TWO 16-trajectory groups (A,B); wave wv owns net wv for
// both groups. Per group: GEMM1 swapped (4 MFMAs), tanh, GEMM2 swapped dense
// K=64 (2 MFMAs). A/B chains are independent -> ILP hides MFMA/TRANS/LDS
// latency; one barrier per step serves both. Weight frags + bias evolution
// shared across groups. State replicated across waves (identical LDS reads).
__global__ __launch_bounds__(256) void sde_mfma8(
    const float* __restrict__ x_real, const float* __restrict__ x_imag,
    const float* __restrict__ params, const float* __restrict__ noise,
    const float* __restrict__ W1, const float* __restrict__ B1,
    const float* __restrict__ W2, const float* __restrict__ B2,
    float* __restrict__ out)
{
    // [dbuf][group][net 4][traj 16][20 floats: 16 used + pad]
    __shared__ __attribute__((aligned(16))) float xbuf[2][2][4][16][20];

    const int tid  = threadIdx.x;
    const int lane = tid & 63;
    const int l15  = lane & 15;
    const int g    = lane >> 4;
    const int wv   = tid >> 6;          // net index 0..3

    // ---- GEMM1 A-frags: h = 16t + l15 (net wv), elem j -> feature 8g+j; *TSC ----
    Frag w1f[4];
    #pragma unroll
    for (int t = 0; t < 4; ++t) {
        const int h = 16 * t + l15;
        #pragma unroll
        for (int j = 0; j < 8; ++j)
            w1f[t].v[j] = f2bf(TSC * W1[(wv * 38 + 1 + 8 * g + j) * 64 + h]);
    }

    // ---- GEMM2 A-frags: row=l15=d, elem j -> h_local = 16*(2kt+(j>>2))+4g+(j&3) ----
    Frag w2f[2];
    #pragma unroll
    for (int kt = 0; kt < 2; ++kt) {
        #pragma unroll
        for (int j = 0; j < 8; ++j) {
            const int hl = 16 * (2 * kt + (j >> 2)) + 4 * g + (j & 3);
            w2f[kt].v[j] = f2bf(W2[(wv * 64 + hl) * 16 + l15]);
        }
    }

    // ---- bias + t-coefficient at C-layout positions (scaled), shared A/B ----
    float pr[5];
    #pragma unroll
    for (int p = 0; p < 5; ++p) pr[p] = params[p];
    f32x4 biascur[4], wtdt[4];
    #pragma unroll
    for (int t = 0; t < 4; ++t) {
        #pragma unroll
        for (int r = 0; r < 4; ++r) {
            const int h = 16 * t + 4 * g + r;
            float b = B1[wv * 64 + h];
            #pragma unroll
            for (int p = 0; p < 5; ++p)
                b = fmaf(pr[p], W1[(wv * 38 + 33 + p) * 64 + h], b);
            biascur[t][r] = TSC * b;
            wtdt[t][r]    = (TSC * DT) * W1[(wv * 38 + 0) * 64 + h];
        }
    }

    // ---- B2 C-in ----
    f32x4 bc;
    #pragma unroll
    for (int r = 0; r < 4; ++r) bc[r] = B2[wv * 16 + 4 * g + r];

    // ---- state: two groups, lane holds comps 8g..8g+7 (replicated per wave) ----
    const int nA = blockIdx.x * 32 + l15;
    const int nB = nA + 16;
    const float* __restrict__ xsrc = (g < 2) ? x_real : x_imag;
    const int xoff = (g & 1) * 8;
    f32x4 stAlo = *reinterpret_cast<const f32x4*>(&xsrc[(nA & (NB - 1)) * 16 + xoff]);
    f32x4 stAhi = *reinterpret_cast<const f32x4*>(&xsrc[(nA & (NB - 1)) * 16 + xoff + 4]);
    f32x4 stBlo = *reinterpret_cast<const f32x4*>(&xsrc[(nB & (NB - 1)) * 16 + xoff]);
    f32x4 stBhi = *reinterpret_cast<const f32x4*>(&xsrc[(nB & (NB - 1)) * 16 + xoff + 4]);

    const float* __restrict__ nspA = noise + (size_t)nA * NSTEP;
    const float* __restrict__ nspB = noise + (size_t)nB * NSTEP;
    float dwA = nspA[0], dwB = nspB[0];

    const int dstep = 2 * 4 * 16 * 20;       // floats per dbuf half
    const int gstep = 4 * 16 * 20;           // floats per group
    float* wrpA         = &xbuf[0][0][wv][l15][4 * g];
    const float* rd_drA = &xbuf[0][0][g >> 1][l15][8 * (g & 1)];
    const float* rd_dfA = &xbuf[0][0][2 + (g >> 1)][l15][8 * (g & 1)];

    for (int s = 0; s < NSTEP; ++s) {
        const int sn = (s + 1 < NSTEP) ? s + 1 : s;
        const float dwAn = nspA[sn], dwBn = nspB[sn];

        // ---- group A: state -> frag, GEMM1, tanh, GEMM2 ----
        Frag bxA;
        bxA.u[0] = pk_bf16(stAlo[0], stAlo[1]);
        bxA.u[1] = pk_bf16(stAlo[2], stAlo[3]);
        bxA.u[2] = pk_bf16(stAhi[0], stAhi[1]);
        bxA.u[3] = pk_bf16(stAhi[2], stAhi[3]);
        Frag bxB;
        bxB.u[0] = pk_bf16(stBlo[0], stBlo[1]);
        bxB.u[1] = pk_bf16(stBlo[2], stBlo[3]);
        bxB.u[2] = pk_bf16(stBhi[0], stBhi[1]);
        bxB.u[3] = pk_bf16(stBhi[2], stBhi[3]);

        f32x4 accA[4], accB[4];
        #pragma unroll
        for (int t = 0; t < 4; ++t)
            accA[t] = __builtin_amdgcn_mfma_f32_16x16x32_bf16(
                w1f[t].v, bxA.v, biascur[t], 0, 0, 0);
        #pragma unroll
        for (int t = 0; t < 4; ++t)
            accB[t] = __builtin_amdgcn_mfma_f32_16x16x32_bf16(
                w1f[t].v, bxB.v, biascur[t], 0, 0, 0);
        #pragma unroll
        for (int t = 0; t < 4; ++t) biascur[t] += wtdt[t];   // shared advance

        f32x4 oA = bc, oB = bc;
        #pragma unroll
        for (int kt = 0; kt < 2; ++kt) {
            const f32x2 a0 = tanh2_sc(accA[2 * kt][0],     accA[2 * kt][1]);
            const f32x2 a1 = tanh2_sc(accA[2 * kt][2],     accA[2 * kt][3]);
            const f32x2 a2 = tanh2_sc(accA[2 * kt + 1][0], accA[2 * kt + 1][1]);
            const f32x2 a3 = tanh2_sc(accA[2 * kt + 1][2], accA[2 * kt + 1][3]);
            Frag pbA;
            pbA.u[0] = pk_bf16(a0.x, a0.y);  pbA.u[1] = pk_bf16(a1.x, a1.y);
            pbA.u[2] = pk_bf16(a2.x, a2.y);  pbA.u[3] = pk_bf16(a3.x, a3.y);
            oA = __builtin_amdgcn_mfma_f32_16x16x32_bf16(w2f[kt].v, pbA.v, oA, 0, 0, 0);

            const f32x2 b0 = tanh2_sc(accB[2 * kt][0],     accB[2 * kt][1]);
            const f32x2 b1 = tanh2_sc(accB[2 * kt][2],     accB[2 * kt][3]);
            const f32x2 b2 = tanh2_sc(accB[2 * kt + 1][0], accB[2 * kt + 1][1]);
            const f32x2 b3 = tanh2_sc(accB[2 * kt + 1][2], accB[2 * kt + 1][3]);
            Frag pbB;
            pbB.u[0] = pk_bf16(b0.x, b0.y);  pbB.u[1] = pk_bf16(b1.x, b1.y);
            pbB.u[2] = pk_bf16(b2.x, b2.y);  pbB.u[3] = pk_bf16(b3.x, b3.y);
            oB = __builtin_amdgcn_mfma_f32_16x16x32_bf16(w2f[kt].v, pbB.v, oB, 0, 0, 0);
        }

        // ---- exchange both groups, one barrier ----
        const int db = s & 1;
        *reinterpret_cast<f32x4*>(wrpA + db * dstep)         = oA;
        *reinterpret_cast<f32x4*>(wrpA + db * dstep + gstep) = oB;
        __syncthreads();
        const float* dpA = rd_drA + db * dstep;
        const float* fpA = rd_dfA + db * dstep;
        const f32x4 drA0 = *reinterpret_cast<const f32x4*>(dpA);
        const f32x4 drA1 = *reinterpret_cast<const f32x4*>(dpA + 4);
        const f32x4 dfA0 = *reinterpret_cast<const f32x4*>(fpA);
        const f32x4 dfA1 = *reinterpret_cast<const f32x4*>(fpA + 4);
        const f32x4 drB0 = *reinterpret_cast<const f32x4*>(dpA + gstep);
        const f32x4 drB1 = *reinterpret_cast<const f32x4*>(dpA + gstep + 4);
        const f32x4 dfB0 = *reinterpret_cast<const f32x4*>(fpA + gstep);
        const f32x4 dfB1 = *reinterpret_cast<const f32x4*>(fpA + gstep + 4);

        // Euler-Maruyama, packed fma
        const f32x4 dt4 = (f32x4)DT;
        const f32x4 dwA4 = (f32x4)dwA, dwB4 = (f32x4)dwB;
        stAlo = __builtin_elementwise_fma(dt4, drA0,
                __builtin_elementwise_fma(dwA4, dfA0, stAlo));
        stAhi = __builtin_elementwise_fma(dt4, drA1,
                __builtin_elementwise_fma(dwA4, dfA1, stAhi));
        stBlo = __builtin_elementwise_fma(dt4, drB0,
                __builtin_elementwise_fma(dwB4, dfB0, stBlo));
        stBhi = __builtin_elementwise_fma(dt4, drB1,
                __builtin_elementwise_fma(dwB4, dfB1, stBhi));
        dwA = dwAn; dwB = dwBn;
    }

    // ---- write out (wave 0 only) ----
    if (wv == 0) {
        float4* opA = reinterpret_cast<float4*>(out + (size_t)nA * 32 + 8 * g);
        opA[0] = make_float4(stAlo[0], stAlo[1], stAlo[2], stAlo[3]);
        opA[1] = make_float4(stAhi[0], stAhi[1], stAhi[2], stAhi[3]);
        float4* opB = reinterpret_cast<float4*>(out + (size_t)nB * 32 + 8 * g);
        opB[0] = make_float4(stBlo[0], stBlo[1], stBlo[2], stBlo[3]);
        opB[1] = make_float4(stBhi[0], stBhi[1], stBhi[2], stBhi[3]);
    }
}

extern "C" void kernel_launch(void* const* d_in, const int* in_sizes, int n_in,
                              void* d_out, int out_size, void* d_ws, size_t ws_size,
                              hipStream_t stream) {
    const float* x_real = (const float*)d_in[0];
    const float* x_imag = (const float*)d_in[1];
    const float* params = (const float*)d_in[2];
    const float* noise  = (const float*)d_in[3];
    const float* W1     = (const float*)d_in[4];
    const float* B1     = (const float*)d_in[5];
    const float* W2     = (const float*)d_in[6];
    const float* B2     = (const float*)d_in[7];
    float* out = (float*)d_out;

    // 512 blocks x 256 threads: 4 waves/block, two 16-traj groups per block
    sde_mfma8<<<dim3(512), dim3(256), 0, stream>>>(
        x_real, x_imag, params, noise, W1, B1, W2, B2, out);
}

// Round 6
// 85.073 us; speedup vs baseline: 1.0568x; 1.0568x over previous
//
#include <hip/hip_runtime.h>
#include <stdint.h>

#define NB    128
#define NSTEP 63
#define DT    0.00390625f
#define TSC   2.8853900817779268f   // 2*log2(e): folded into GEMM1 weights/bias

typedef __attribute__((ext_vector_type(8))) short bf16x8;
typedef __attribute__((ext_vector_type(4))) float f32x4;
typedef __attribute__((ext_vector_type(2))) float f32x2;

union Frag { bf16x8 v; uint32_t u[4]; };

__device__ __forceinline__ short f2bf(float f) {
    uint32_t u = __float_as_uint(f);
    u += 0x7FFF + ((u >> 16) & 1);          // round-to-nearest-even
    return (short)(u >> 16);
}

__device__ __forceinline__ uint32_t pk_bf16(float lo, float hi) {
    uint32_t r;
    asm("v_cvt_pk_bf16_f32 %0, %1, %2" : "=v"(r) : "v"(lo), "v"(hi));
    return r;
}

// Pairwise tanh on pre-scaled inputs y = 2*log2e*preact: tanh = 1 - 2/(2^y+1).
// Builtins only (TRANS wait-state hazard: inline-asm exp broke round 3).
__device__ __forceinline__ f32x2 tanh2_sc(float y0, float y1) {
    f32x2 e = { __builtin_amdgcn_exp2f(y0), __builtin_amdgcn_exp2f(y1) };
    f32x2 ep = e + (f32x2)1.0f;
    f32x2 r = { __builtin_amdgcn_rcpf(ep.x), __builtin_amdgcn_rcpf(ep.y) };
    return __builtin_elementwise_fma(r, (f32x2)(-2.0f), (f32x2)(1.0f));
}

// ONE WAVE = 16 trajectories x ALL 4 nets. No LDS, no barrier, no cross-lane.
// Feature permutation: GEMM1 k-slot (g,j) -> (j<4 ? Re[4g+j] : Im[4g+j-4]),
// so each lane's B-frag is its own 8 state comps. GEMM1: 16 MFMAs (256 h).
// Hidden permutation (as R4): GEMM1 C-layout == GEMM2 B-frag slots, dense
// GEMM2 K=64 per net = 8 MFMAs. GEMM2 C-layout rows 4g+r = dims 4g..4g+3 ->
// lane holds all 4 nets' outputs at its own dims -> lane-local state update.
// 1024 waves (1/SIMD); VGPR-heavy (~400) is fine at 1 wave/SIMD.
__global__ __launch_bounds__(256, 1) void sde_1wave(
    const float* __restrict__ x_real, const float* __restrict__ x_imag,
    const float* __restrict__ params, const float* __restrict__ noise,
    const float* __restrict__ W1, const float* __restrict__ B1,
    const float* __restrict__ W2, const float* __restrict__ B2,
    float* __restrict__ out)
{
    const int tid  = threadIdx.x;
    const int lane = tid & 63;
    const int l15  = lane & 15;
    const int g    = lane >> 4;
    const int wv   = tid >> 6;
    const int wid  = blockIdx.x * 4 + wv;   // global wave id, 0..1023
    const int n    = wid * 16 + l15;        // this lane's trajectory

    // ---- GEMM1 A-frags: tile t -> h-col c1 = 16t+l15 (net=t>>2), elem j ->
    //      permuted feature: j<4 -> Re[4g+j] (W1 row 1+4g+j),
    //      j>=4 -> Im[4g+j-4] (W1 row 17+4g+j-4); pre-scaled by TSC ----
    Frag w1f[16];
    #pragma unroll
    for (int t = 0; t < 16; ++t) {
        const int net = t >> 2;
        const int hn  = 16 * (t & 3) + l15;
        #pragma unroll
        for (int j = 0; j < 8; ++j) {
            const int jf = (j < 4) ? (4 * g + j) : (16 + 4 * g + (j - 4));
            w1f[t].v[j] = f2bf(TSC * W1[(net * 38 + 1 + jf) * 64 + hn]);
        }
    }

    // ---- GEMM2 A-frags: net k, kt; row=l15=d, elem j -> h_local ----
    Frag w2f[4][2];
    #pragma unroll
    for (int k = 0; k < 4; ++k)
        #pragma unroll
        for (int kt = 0; kt < 2; ++kt)
            #pragma unroll
            for (int j = 0; j < 8; ++j) {
                const int hl = 16 * (2 * kt + (j >> 2)) + 4 * g + (j & 3);
                w2f[k][kt].v[j] = f2bf(W2[(k * 64 + hl) * 16 + l15]);
            }

    // ---- bias + t-coefficient at C-layout positions (scaled by TSC) ----
    float pr[5];
    #pragma unroll
    for (int p = 0; p < 5; ++p) pr[p] = params[p];
    f32x4 biascur[16], wtdt[16];
    #pragma unroll
    for (int t = 0; t < 16; ++t) {
        #pragma unroll
        for (int r = 0; r < 4; ++r) {
            const int c1 = 16 * t + 4 * g + r;
            const int net = c1 >> 6, h = c1 & 63;
            float b = B1[net * 64 + h];
            #pragma unroll
            for (int p = 0; p < 5; ++p)
                b = fmaf(pr[p], W1[(net * 38 + 33 + p) * 64 + h], b);
            biascur[t][r] = TSC * b;
            wtdt[t][r]    = (TSC * DT) * W1[(net * 38 + 0) * 64 + h];
        }
    }

    // ---- B2 C-in per net: rows 4g+r = dims 4g..4g+3 ----
    f32x4 bc[4];
    #pragma unroll
    for (int k = 0; k < 4; ++k)
        #pragma unroll
        for (int r = 0; r < 4; ++r) bc[k][r] = B2[k * 16 + 4 * g + r];

    // ---- state: lane holds Re[4g..4g+3], Im[4g..4g+3] of traj n ----
    const int xrow = n & (NB - 1);
    f32x4 sre = *reinterpret_cast<const f32x4*>(&x_real[xrow * 16 + 4 * g]);
    f32x4 sim = *reinterpret_cast<const f32x4*>(&x_imag[xrow * 16 + 4 * g]);

    const float* __restrict__ nsp = noise + (size_t)n * NSTEP;
    float dw = nsp[0];

    for (int s = 0; s < NSTEP; ++s) {
        const float dwn = nsp[(s + 1 < NSTEP) ? s + 1 : s];

        // state -> B-frag: slots 8g+j = (j<4 ? Re[4g+j] : Im[4g+j-4])
        Frag bx;
        bx.u[0] = pk_bf16(sre[0], sre[1]);
        bx.u[1] = pk_bf16(sre[2], sre[3]);
        bx.u[2] = pk_bf16(sim[0], sim[1]);
        bx.u[3] = pk_bf16(sim[2], sim[3]);

        // GEMM1: 16 independent MFMAs over all 4 nets' hidden columns
        f32x4 acc[16];
        #pragma unroll
        for (int t = 0; t < 16; ++t)
            acc[t] = __builtin_amdgcn_mfma_f32_16x16x32_bf16(
                w1f[t].v, bx.v, biascur[t], 0, 0, 0);
        #pragma unroll
        for (int t = 0; t < 16; ++t) biascur[t] += wtdt[t];

        // tanh of all 64 values in one batch (64 independent TRANS chains)
        f32x4 th[16];
        #pragma unroll
        for (int t = 0; t < 16; ++t) {
            const f32x2 lo = tanh2_sc(acc[t][0], acc[t][1]);
            const f32x2 hi = tanh2_sc(acc[t][2], acc[t][3]);
            th[t][0] = lo.x; th[t][1] = lo.y; th[t][2] = hi.x; th[t][3] = hi.y;
        }

        // GEMM2: dense K=64 per net, 2 MFMAs each
        f32x4 o[4];
        #pragma unroll
        for (int k = 0; k < 4; ++k) {
            o[k] = bc[k];
            #pragma unroll
            for (int kt = 0; kt < 2; ++kt) {
                const int T0 = 4 * k + 2 * kt;
                Frag pb;
                pb.u[0] = pk_bf16(th[T0][0],     th[T0][1]);
                pb.u[1] = pk_bf16(th[T0][2],     th[T0][3]);
                pb.u[2] = pk_bf16(th[T0 + 1][0], th[T0 + 1][1]);
                pb.u[3] = pk_bf16(th[T0 + 1][2], th[T0 + 1][3]);
                o[k] = __builtin_amdgcn_mfma_f32_16x16x32_bf16(
                    w2f[k][kt].v, pb.v, o[k], 0, 0, 0);
            }
        }

        // Euler-Maruyama: x += a*dt + b*dw, fully lane-local
        const f32x4 dt4 = (f32x4)DT;
        const f32x4 dw4 = (f32x4)dw;
        sre = __builtin_elementwise_fma(dt4, o[0],
              __builtin_elementwise_fma(dw4, o[2], sre));
        sim = __builtin_elementwise_fma(dt4, o[1],
              __builtin_elementwise_fma(dw4, o[3], sim));
        dw = dwn;
    }

    // ---- write out: Re at [n*32 + 4g], Im at [n*32 + 16 + 4g] ----
    *reinterpret_cast<f32x4*>(out + (size_t)n * 32 + 4 * g)      = sre;
    *reinterpret_cast<f32x4*>(out + (size_t)n * 32 + 16 + 4 * g) = sim;
}

extern "C" void kernel_launch(void* const* d_in, const int* in_sizes, int n_in,
                              void* d_out, int out_size, void* d_ws, size_t ws_size,
                              hipStream_t stream) {
    const float* x_real = (const float*)d_in[0];
    const float* x_imag = (const float*)d_in[1];
    const float* params = (const float*)d_in[2];
    const float* noise  = (const float*)d_in[3];
    const float* W1     = (const float*)d_in[4];
    const float* B1     = (const float*)d_in[5];
    const float* W2     = (const float*)d_in[6];
    const float* B2     = (const float*)d_in[7];
    float* out = (float*)d_out;

    // 256 blocks x 256 threads = 1024 waves; each wave owns 16 trajectories
    sde_1wave<<<dim3(256), dim3(256), 0, stream>>>(
        x_real, x_imag, params, noise, W1, B1, W2, B2, out);
}